// Round 3
// baseline (574.856 us; speedup 1.0000x reference)
//
#include <hip/hip_runtime.h>

// Problem constants: B=4, N=1024, E=1024, H=16, Dh=64, BH=B*H=64, M=B*N=4096.
// Permutation (faithful "buggy view"): row r=b*1024+n, col e:
//   bh=(n%4)*16 + e/64 ; n2=b*256 + n/4 ; d=e%64
// Output attn[b2][i][e2]: b2=bh/16, e2=(bh%16)*64+d, i=n2-domain row.

using f32x4 = __attribute__((ext_vector_type(4))) float;
using f16x8 = __attribute__((ext_vector_type(8))) _Float16;
using f16x4 = __attribute__((ext_vector_type(4))) _Float16;

#define MFMA16(a, b, c) __builtin_amdgcn_mfma_f32_16x16x32_f16(a, b, c, 0, 0, 0)

// ---------------------------------------------------------------------------
// K1: fused-cast projection GEMM.  C[r][e] = sum_k X[r][k]*W[e][k] + bias[e]
// 128x128 tile, BK=32, 4 waves (2x2), 16x16x32 f16 MFMA, fp16 output stored
// in permuted [bh][n2][d] layout.
// ---------------------------------------------------------------------------
__global__ __launch_bounds__(256) void proj_kernel(
    const float* __restrict__ Xq, const float* __restrict__ Xk,
    const float* __restrict__ Xv, const float* __restrict__ Wq_,
    const float* __restrict__ Wk_, const float* __restrict__ Wv_,
    const float* __restrict__ bq_, const float* __restrict__ bk_,
    const float* __restrict__ bv_, _Float16* __restrict__ qp,
    _Float16* __restrict__ kp, _Float16* __restrict__ vp)
{
    const int mat = blockIdx.z;
    const float* X    = (mat == 0) ? Xq  : (mat == 1) ? Xk  : Xv;
    const float* W    = (mat == 0) ? Wq_ : (mat == 1) ? Wk_ : Wv_;
    const float* bias = (mat == 0) ? bq_ : (mat == 1) ? bk_ : bv_;
    _Float16* out     = (mat == 0) ? qp  : (mat == 1) ? kp  : vp;

    const int tid = threadIdx.x;
    const int m0 = blockIdx.y * 128;   // row tile in [0,4096)
    const int e0 = blockIdx.x * 128;   // col tile in [0,1024)

    // LDS tiles, stride 40 halves = 80B (16B aligned, 2-way banks => free)
    __shared__ _Float16 Abuf[2][128 * 40];
    __shared__ _Float16 Bbuf[2][128 * 40];

    const int srow = tid >> 3;          // 0..31 (4 rows per thread, stride 32)
    const int scol = (tid & 7) << 2;    // 0..28 step 4 (float4)

    const int wave = tid >> 6;
    const int lane = tid & 63;
    const int wm = (wave >> 1) << 6;    // 0 / 64
    const int wn = (wave & 1) << 6;     // 0 / 64
    const int lr = lane & 15;
    const int lk = lane >> 4;

    f32x4 acc[4][4];
#pragma unroll
    for (int m = 0; m < 4; ++m)
#pragma unroll
        for (int n = 0; n < 4; ++n) acc[m][n] = (f32x4){0.f, 0.f, 0.f, 0.f};

    const float* Xp = X + (m0 + srow) * 1024 + scol;
    const float* Wp = W + (e0 + srow) * 1024 + scol;

    f32x4 ra[4], rb[4];
#pragma unroll
    for (int i = 0; i < 4; ++i) {
        ra[i] = *(const f32x4*)(Xp + i * 32 * 1024);
        rb[i] = *(const f32x4*)(Wp + i * 32 * 1024);
    }

    auto cvt_store = [&](int buf) {
#pragma unroll
        for (int i = 0; i < 4; ++i) {
            f16x4 a, b;
#pragma unroll
            for (int j = 0; j < 4; ++j) {
                a[j] = (_Float16)ra[i][j];
                b[j] = (_Float16)rb[i][j];
            }
            *(f16x4*)&Abuf[buf][(srow + 32 * i) * 40 + scol] = a;
            *(f16x4*)&Bbuf[buf][(srow + 32 * i) * 40 + scol] = b;
        }
    };

    cvt_store(0);
    __syncthreads();

    for (int kt = 0; kt < 32; ++kt) {
        const int cur = kt & 1;
        if (kt < 31) {
#pragma unroll
            for (int i = 0; i < 4; ++i) {
                ra[i] = *(const f32x4*)(Xp + (kt + 1) * 32 + i * 32 * 1024);
                rb[i] = *(const f32x4*)(Wp + (kt + 1) * 32 + i * 32 * 1024);
            }
        }
        f16x8 af[4], bf[4];
#pragma unroll
        for (int m = 0; m < 4; ++m)
            af[m] = *(const f16x8*)&Abuf[cur][(wm + m * 16 + lr) * 40 + lk * 8];
#pragma unroll
        for (int n = 0; n < 4; ++n)
            bf[n] = *(const f16x8*)&Bbuf[cur][(wn + n * 16 + lr) * 40 + lk * 8];
#pragma unroll
        for (int m = 0; m < 4; ++m)
#pragma unroll
            for (int n = 0; n < 4; ++n)
                acc[m][n] = MFMA16(af[m], bf[n], acc[m][n]);
        if (kt < 31) cvt_store(1 - cur);
        __syncthreads();
    }

    // Epilogue: bias + cast + permuted store (d stays contiguous => 32B runs)
    float bcol[4];
#pragma unroll
    for (int n = 0; n < 4; ++n) bcol[n] = bias[e0 + wn + n * 16 + lr];

#pragma unroll
    for (int m = 0; m < 4; ++m) {
        const int rowb = m0 + wm + m * 16 + lk * 4;
#pragma unroll
        for (int r = 0; r < 4; ++r) {
            const int row = rowb + r;
            const int b  = row >> 10;
            const int ns = row & 1023;
            const int n2 = (b << 8) + (ns >> 2);
            const int bh_base = (ns & 3) << 4;
#pragma unroll
            for (int n = 0; n < 4; ++n) {
                const int col = e0 + wn + n * 16 + lr;
                const int bh  = bh_base + (col >> 6);
                const int d   = col & 63;
                out[(size_t)((bh << 10) + n2) * 64 + d] =
                    (_Float16)(acc[m][n][r] + bcol[n]);
            }
        }
    }
}

// ---------------------------------------------------------------------------
// K1b: transpose vp [bh][j][d] -> vpT [bh][d][j] so PV B-fragments are
// contiguous 16B per-lane reads.
// ---------------------------------------------------------------------------
__global__ __launch_bounds__(256) void vtrans_kernel(
    const _Float16* __restrict__ vp, _Float16* __restrict__ vpT)
{
    const int bh = blockIdx.y;
    const int j0 = blockIdx.x * 64;
    __shared__ _Float16 t[64][72];   // pad to 72 (144B stride, 16B aligned)
    const int tid = threadIdx.x;
    const int row = tid >> 3;
    const int c8 = (tid & 7) * 8;
#pragma unroll
    for (int i = 0; i < 2; ++i) {
        f16x8 v = *(const f16x8*)(vp + (size_t)((bh << 10) + j0 + row + 32 * i) * 64 + c8);
        *(f16x8*)&t[row + 32 * i][c8] = v;
    }
    __syncthreads();
    const int d = tid >> 2;          // 0..63
#pragma unroll
    for (int g = 0; g < 2; ++g) {
        const int j8 = ((tid & 3) * 2 + g) * 8;
        f16x8 v;
#pragma unroll
        for (int w = 0; w < 8; ++w) v[w] = t[j8 + w][d];
        *(f16x8*)(vpT + (size_t)((bh << 6) + d) * 1024 + j0 + j8) = v;
    }
}

// ---------------------------------------------------------------------------
// K2: attention.  Per wave: 16 queries of one bh.
// Pass 1: row sums of exp(S+bias) (no max-sub: |S|<~50 is fp32-safe).
// Pass 2: recompute S (deterministic), write normalized weights (fp32),
//         accumulate PV via MFMA (P relayout through tiny per-wave LDS).
// ---------------------------------------------------------------------------
__global__ __launch_bounds__(256) void attn_kernel(
    const _Float16* __restrict__ qp, const _Float16* __restrict__ kp,
    const _Float16* __restrict__ vpT, const float* __restrict__ bias,
    float* __restrict__ out_attn, float* __restrict__ out_w)
{
    const int bh = blockIdx.y;
    const int tid = threadIdx.x;
    const int wave = tid >> 6;
    const int lane = tid & 63;
    const int i0 = blockIdx.x * 64 + wave * 16;
    const int lr = lane & 15;
    const int lk = lane >> 4;

    __shared__ _Float16 plds[4][2][16 * 40];  // per-wave double-buffered P

    const _Float16* qb = qp + (size_t)(bh << 10) * 64;
    const _Float16* kb = kp + (size_t)(bh << 10) * 64;
    const _Float16* vb = vpT + (size_t)(bh << 6) * 1024;
    const float* bb = bias + (size_t)(bh & 3) * 1048576;
    float* wout = out_w + (size_t)bh * 1048576;

    const f16x8 aq0 = *(const f16x8*)(qb + (i0 + lr) * 64 + lk * 8);
    const f16x8 aq1 = *(const f16x8*)(qb + (i0 + lr) * 64 + 32 + lk * 8);
    const int rowb = i0 + lk * 4;

    // ---- pass 1: denominators ----
    float suml[4] = {0.f, 0.f, 0.f, 0.f};
    for (int j0 = 0; j0 < 1024; j0 += 16) {
        f16x8 bk0 = *(const f16x8*)(kb + (j0 + lr) * 64 + lk * 8);
        f16x8 bk1 = *(const f16x8*)(kb + (j0 + lr) * 64 + 32 + lk * 8);
        f32x4 s = (f32x4){0.f, 0.f, 0.f, 0.f};
        s = MFMA16(aq0, bk0, s);
        s = MFMA16(aq1, bk1, s);
#pragma unroll
        for (int r = 0; r < 4; ++r) {
            float sc = s[r] + bb[(rowb + r) * 1024 + j0 + lr];
            suml[r] += __expf(sc);
        }
    }
#pragma unroll
    for (int r = 0; r < 4; ++r) {
        float v = suml[r];
        v += __shfl_xor(v, 1, 64);
        v += __shfl_xor(v, 2, 64);
        v += __shfl_xor(v, 4, 64);
        v += __shfl_xor(v, 8, 64);
        suml[r] = 1.0f / v;   // now reciprocal denominator for rows rowb+r
    }

    // ---- pass 2: weights + PV ----
    f32x4 acco[4];
#pragma unroll
    for (int dt = 0; dt < 4; ++dt) acco[dt] = (f32x4){0.f, 0.f, 0.f, 0.f};

    int buf = 0;
    for (int jc = 0; jc < 1024; jc += 32) {
#pragma unroll
        for (int t = 0; t < 2; ++t) {
            const int j0 = jc + t * 16;
            f16x8 bk0 = *(const f16x8*)(kb + (j0 + lr) * 64 + lk * 8);
            f16x8 bk1 = *(const f16x8*)(kb + (j0 + lr) * 64 + 32 + lk * 8);
            f32x4 s = (f32x4){0.f, 0.f, 0.f, 0.f};
            s = MFMA16(aq0, bk0, s);
            s = MFMA16(aq1, bk1, s);
#pragma unroll
            for (int r = 0; r < 4; ++r) {
                float sc = s[r] + bb[(rowb + r) * 1024 + j0 + lr];
                float w = __expf(sc) * suml[r];
                wout[(rowb + r) * 1024 + j0 + lr] = w;
                plds[wave][buf][(lk * 4 + r) * 40 + t * 16 + lr] = (_Float16)w;
            }
        }
        // order the cross-lane LDS write->read within the wave
        asm volatile("s_waitcnt lgkmcnt(0)" ::: "memory");
        __builtin_amdgcn_sched_barrier(0);
        f16x8 ap = *(const f16x8*)&plds[wave][buf][lr * 40 + lk * 8];
#pragma unroll
        for (int dt = 0; dt < 4; ++dt) {
            f16x8 bvv = *(const f16x8*)(vb + (dt * 16 + lr) * 1024 + jc + lk * 8);
            acco[dt] = MFMA16(ap, bvv, acco[dt]);
        }
        buf ^= 1;
    }

    // ---- epilogue: attn output (already normalized; P used normalized) ----
    const int b2 = bh >> 4;
    const int e_hi = (bh & 15) << 6;
    float* ob = out_attn + (size_t)b2 * 1048576;
#pragma unroll
    for (int dt = 0; dt < 4; ++dt)
#pragma unroll
        for (int r = 0; r < 4; ++r)
            ob[(rowb + r) * 1024 + e_hi + dt * 16 + lr] = acco[dt][r];
}

// ---------------------------------------------------------------------------
extern "C" void kernel_launch(void* const* d_in, const int* in_sizes, int n_in,
                              void* d_out, int out_size, void* d_ws, size_t ws_size,
                              hipStream_t stream)
{
    const float* query = (const float*)d_in[0];
    const float* key   = (const float*)d_in[1];
    const float* value = (const float*)d_in[2];
    const float* bias  = (const float*)d_in[3];
    const float* Wq    = (const float*)d_in[4];
    const float* bq    = (const float*)d_in[5];
    const float* Wk    = (const float*)d_in[6];
    const float* bk    = (const float*)d_in[7];
    const float* Wv    = (const float*)d_in[8];
    const float* bv    = (const float*)d_in[9];

    float* out_attn = (float*)d_out;                 // [4][1024][1024]
    float* out_w    = (float*)d_out + 4194304;       // [64][1024][1024]

    char* ws = (char*)d_ws;                          // needs 32 MiB
    _Float16* qp  = (_Float16*)(ws);                 // [64][1024][64]
    _Float16* kp  = (_Float16*)(ws + 8388608);
    _Float16* vp  = (_Float16*)(ws + 16777216);
    _Float16* vpT = (_Float16*)(ws + 25165824);      // [64][64][1024]

    proj_kernel<<<dim3(8, 32, 3), 256, 0, stream>>>(
        query, key, value, Wq, Wk, Wv, bq, bk, bv, qp, kp, vp);
    vtrans_kernel<<<dim3(16, 64), 256, 0, stream>>>(vp, vpT);
    attn_kernel<<<dim3(16, 64), 256, 0, stream>>>(
        qp, kp, vpT, bias, out_attn, out_w);
}